// Round 7
// baseline (135.628 us; speedup 1.0000x reference)
//
#include <hip/hip_runtime.h>

#define BLOCK 256
#define GRID  2048
#define NWAVE (BLOCK / 64)
#define DEPTH 4

typedef int v4i __attribute__((ext_vector_type(4)));

#define AS3P(p) ((__attribute__((address_space(3))) void*)(p))
#define AS1P(p) ((const __attribute__((address_space(1))) void*)(p))

#define PROC(XC, TC)                                        \
    {                                                       \
        float xi = (XC); int ti = (TC);                     \
        float a = ti ? xi : (1.0f - xi);                    \
        float v = __log2f(a);   /* negative; scaled by -ln2 in finalize */ \
        tot += v;                                           \
        pos += ti ? v : 0.0f;                               \
        cnt += ti;                                          \
    }

#define PROC4(xv, tv) \
    PROC(xv.x, tv.x) PROC(xv.y, tv.y) PROC(xv.z, tv.z) PROC(xv.w, tv.w)

#define FENCE() __builtin_amdgcn_sched_barrier(0)

__global__ __launch_bounds__(BLOCK) void wbce_reduce_kernel(
    const float* __restrict__ x, const int* __restrict__ t,
    long long n, double* __restrict__ ws) {
    const int tid  = threadIdx.x;
    const int lane = tid & 63;
    const int wv   = tid >> 6;

    const long long n4 = n >> 2;
    const long long waves_total = (long long)GRID * NWAVE;
    const int nst = (int)(n4 / (waves_total * 64));   // stages per wave
    const long long main_f4 = waves_total * 64 * (long long)nst;

    float tot = 0.0f, pos = 0.0f;                     // sums of log2(a)
    int cnt = 0;

    // per-wave DEPTH-deep double buffers; no cross-wave sharing -> no barriers
    __shared__ float4 sx[NWAVE][DEPTH][64];
    __shared__ v4i    st[NWAVE][DEPTH][64];

    if (nst >= DEPTH) {
        const int wid = blockIdx.x * NWAVE + wv;
        const long long wbase = (long long)wid * 64 * nst;   // float4 units
        const float4* gxs = ((const float4*)x) + wbase + lane;
        const v4i*    gts = ((const v4i*)t)   + wbase + lane;

        // x cached (stays L3-resident); t non-temporal (aux NT bit) streams HBM
#define ISSUE_STAGE(STG) do {                                                 \
        const int _sl = (STG) & (DEPTH - 1);                                  \
        __builtin_amdgcn_global_load_lds(AS1P(gxs + (long long)(STG) * 64),   \
                                         AS3P(&sx[wv][_sl][0]), 16, 0, 0);    \
        __builtin_amdgcn_global_load_lds(AS1P(gts + (long long)(STG) * 64),   \
                                         AS3P(&st[wv][_sl][0]), 16, 0, 2);    \
    } while (0)

        ISSUE_STAGE(0); ISSUE_STAGE(1); ISSUE_STAGE(2); ISSUE_STAGE(3);

        for (int s = 0; s < nst; ++s) {
            const int rem = nst - 1 - s;   // stages outstanding after this one
            if (rem >= 3)      { asm volatile("s_waitcnt vmcnt(6)" ::: "memory"); }
            else if (rem == 2) { asm volatile("s_waitcnt vmcnt(4)" ::: "memory"); }
            else if (rem == 1) { asm volatile("s_waitcnt vmcnt(2)" ::: "memory"); }
            else               { asm volatile("s_waitcnt vmcnt(0)" ::: "memory"); }
            FENCE();

            float4 xv = sx[wv][s & (DEPTH - 1)][lane];
            v4i    tv = st[wv][s & (DEPTH - 1)][lane];

            // WAR fence: ds_reads must land in VGPRs before slot is re-filled
            asm volatile("s_waitcnt lgkmcnt(0)" ::: "memory");
            FENCE();

            if (s + DEPTH < nst) ISSUE_STAGE(s + DEPTH);

            PROC4(xv, tv)
        }
#undef ISSUE_STAGE
    }

    // remainder of float4-aligned region (grid-stride, plain HIP)
    {
        const float4* __restrict__ x4 = (const float4*)x;
        const v4i*    __restrict__ t4 = (const v4i*)t;
        for (long long i = main_f4 + (long long)blockIdx.x * BLOCK + tid;
             i < n4; i += (long long)GRID * BLOCK) {
            float4 xv = x4[i];
            v4i    tv = __builtin_nontemporal_load(&t4[i]);
            PROC4(xv, tv)
        }
    }

    // scalar tail (n not divisible by 4)
    if (blockIdx.x == 0 && tid == 0) {
        for (long long i = n4 << 2; i < n; ++i) {
            float xi = x[i]; int ti = t[i];
            float a = ti ? xi : (1.0f - xi);
            float v = __log2f(a);
            tot += v;
            pos += ti ? v : 0.0f;
            cnt += ti;
        }
    }

    float neg = tot - pos;

    // wave reduction (64 lanes)
    for (int o = 32; o > 0; o >>= 1) {
        pos += __shfl_down(pos, o);
        neg += __shfl_down(neg, o);
        cnt += __shfl_down(cnt, o);
    }

    __shared__ float s_pos[NWAVE];
    __shared__ float s_neg[NWAVE];
    __shared__ int   s_cnt[NWAVE];
    if (lane == 0) {
        s_pos[wv] = pos;
        s_neg[wv] = neg;
        s_cnt[wv] = cnt;
    }
    __syncthreads();

    if (tid == 0) {
        double bpos = 0.0, bneg = 0.0;
        long long bcnt = 0;
        for (int w = 0; w < NWAVE; ++w) {
            bpos += (double)s_pos[w];
            bneg += (double)s_neg[w];
            bcnt += s_cnt[w];
        }
        atomicAdd(&ws[0], (double)bcnt);
        atomicAdd(&ws[1], bpos);
        atomicAdd(&ws[2], bneg);
    }
}

__global__ void wbce_finalize_kernel(const double* __restrict__ ws,
                                     float* __restrict__ out, double n) {
    const double LN2 = 0.6931471805599453;
    double s   = ws[0];
    double pos = -ws[1] * LN2;   // sums were log2(a) (negative)
    double neg = -ws[2] * LN2;
    double len = n + 1.0;
    double wp  = len / (s + 1.0);
    double wn  = len / (len - s);
    double loss = ((wp + 1.0) * pos + (wn + 1.0) * neg) / n;
    out[0] = (float)loss;
}

extern "C" void kernel_launch(void* const* d_in, const int* in_sizes, int n_in,
                              void* d_out, int out_size, void* d_ws, size_t ws_size,
                              hipStream_t stream) {
    const float* x = (const float*)d_in[0];
    const int*   t = (const int*)d_in[1];
    float* out = (float*)d_out;
    double* ws = (double*)d_ws;
    const long long n = (long long)in_sizes[0];

    hipMemsetAsync(ws, 0, 3 * sizeof(double), stream);
    wbce_reduce_kernel<<<GRID, BLOCK, 0, stream>>>(x, t, n, ws);
    wbce_finalize_kernel<<<1, 1, 0, stream>>>(ws, out, (double)n);
}

// Round 8
// 130.219 us; speedup vs baseline: 1.0415x; 1.0415x over previous
//
#include <hip/hip_runtime.h>

#define BLOCK 256
#define GRID 2048
#define UNROLL 4

typedef int   v4i __attribute__((ext_vector_type(4)));
typedef float v4f __attribute__((ext_vector_type(4)));

__global__ __launch_bounds__(BLOCK) void wbce_reduce_kernel(
    const float* __restrict__ x, const int* __restrict__ t,
    long long n, double* __restrict__ ws) {
    const long long n4 = n >> 2;
    const long long idx = (long long)blockIdx.x * BLOCK + threadIdx.x;
    const long long stride = (long long)GRID * BLOCK;

    // tot = pos + neg; neg derived afterwards
    float tot = 0.0f, pos = 0.0f;
    int cnt = 0;

    const v4f* __restrict__ x4 = (const v4f*)x;
    const v4i* __restrict__ t4 = (const v4i*)t;

#define PROC(XC, TC)                                        \
    {                                                       \
        float xi = (XC); int ti = (TC);                     \
        float a = ti ? xi : (1.0f - xi);                    \
        float v = -__logf(a);                               \
        tot += v;                                           \
        pos += ti ? v : 0.0f;                               \
        cnt += ti ? 1 : 0;                                  \
    }

    const long long chunk = stride * UNROLL;
    const long long n4_main = n4 - (n4 % chunk);

    // BOTH streams non-temporal: no L3 allocation, pure HBM streaming read.
    // (A/B vs R6 which cached x in L3: isolates the L3-hit service rate.)
    for (long long base = idx; base < n4_main; base += chunk) {
        v4f xv[UNROLL];
        v4i tv[UNROLL];
#pragma unroll
        for (int j = 0; j < UNROLL; ++j)
            xv[j] = __builtin_nontemporal_load(&x4[base + (long long)j * stride]);
#pragma unroll
        for (int j = 0; j < UNROLL; ++j)
            tv[j] = __builtin_nontemporal_load(&t4[base + (long long)j * stride]);
#pragma unroll
        for (int j = 0; j < UNROLL; ++j) {
            PROC(xv[j].x, tv[j].x)
            PROC(xv[j].y, tv[j].y)
            PROC(xv[j].z, tv[j].z)
            PROC(xv[j].w, tv[j].w)
        }
    }

    // remainder of float4-aligned region
    for (long long i = n4_main + idx; i < n4; i += stride) {
        v4f xv = __builtin_nontemporal_load(&x4[i]);
        v4i tv = __builtin_nontemporal_load(&t4[i]);
        PROC(xv.x, tv.x)
        PROC(xv.y, tv.y)
        PROC(xv.z, tv.z)
        PROC(xv.w, tv.w)
    }

    // scalar tail (n not divisible by 4) — block 0 thread 0
    if (idx == 0) {
        for (long long i = n4 << 2; i < n; ++i) {
            float xi = x[i]; int ti = t[i];
            float a = ti ? xi : (1.0f - xi);
            float v = -__logf(a);
            tot += v;
            pos += ti ? v : 0.0f;
            cnt += ti ? 1 : 0;
        }
    }
#undef PROC

    float neg = tot - pos;

    // wave reduction (64 lanes)
    for (int o = 32; o > 0; o >>= 1) {
        pos += __shfl_down(pos, o);
        neg += __shfl_down(neg, o);
        cnt += __shfl_down(cnt, o);
    }

    __shared__ float s_pos[BLOCK / 64];
    __shared__ float s_neg[BLOCK / 64];
    __shared__ int   s_cnt[BLOCK / 64];
    const int lane = threadIdx.x & 63;
    const int wave = threadIdx.x >> 6;
    if (lane == 0) {
        s_pos[wave] = pos;
        s_neg[wave] = neg;
        s_cnt[wave] = cnt;
    }
    __syncthreads();

    if (threadIdx.x == 0) {
        double bpos = 0.0, bneg = 0.0;
        long long bcnt = 0;
        for (int w = 0; w < BLOCK / 64; ++w) {
            bpos += (double)s_pos[w];
            bneg += (double)s_neg[w];
            bcnt += s_cnt[w];
        }
        atomicAdd(&ws[0], (double)bcnt);
        atomicAdd(&ws[1], bpos);
        atomicAdd(&ws[2], bneg);
    }
}

__global__ void wbce_finalize_kernel(const double* __restrict__ ws,
                                     float* __restrict__ out, double n) {
    double s   = ws[0];
    double pos = ws[1];
    double neg = ws[2];
    double len = n + 1.0;
    double wp  = len / (s + 1.0);
    double wn  = len / (len - s);
    double loss = ((wp + 1.0) * pos + (wn + 1.0) * neg) / n;
    out[0] = (float)loss;
}

extern "C" void kernel_launch(void* const* d_in, const int* in_sizes, int n_in,
                              void* d_out, int out_size, void* d_ws, size_t ws_size,
                              hipStream_t stream) {
    const float* x = (const float*)d_in[0];
    const int*   t = (const int*)d_in[1];
    float* out = (float*)d_out;
    double* ws = (double*)d_ws;
    const long long n = (long long)in_sizes[0];

    hipMemsetAsync(ws, 0, 3 * sizeof(double), stream);
    wbce_reduce_kernel<<<GRID, BLOCK, 0, stream>>>(x, t, n, ws);
    wbce_finalize_kernel<<<1, 1, 0, stream>>>(ws, out, (double)n);
}